// Round 1
// baseline (861.034 us; speedup 1.0000x reference)
//
#include <hip/hip_runtime.h>
#include <cstdint>
#include <cstddef>

#define CE 768
#define CD 512
#define NB 64
#define HH 28
#define WW 28
#define HP 30
#define WP 30
#define POS 784            // 28*28
#define M_TOT 50176        // 64*784
#define K_TOT 6912         // 9*768

typedef _Float16 f16x8 __attribute__((ext_vector_type(8)));
typedef float f32x4 __attribute__((ext_vector_type(4)));

// ---------------- kernel 1: weight transpose + cast ----------------
// conv_w [CD][CE][3][3] fp32 -> wT [CD][9*CE] f16 with k = tap*CE + ci
__global__ void prep_w_kernel(const float* __restrict__ cw, _Float16* __restrict__ wT) {
  int co = blockIdx.x;
  const float* src = cw + (size_t)co * CE * 9;
  _Float16* dst = wT + (size_t)co * K_TOT;
  for (int j = threadIdx.x; j < K_TOT; j += blockDim.x) {
    int tap = j / CE;              // dh*3+dw
    int ci = j - tap * CE;
    dst[j] = (_Float16)src[ci * 9 + tap];
  }
}

// ---------------- kernel 2: LN stats partial sums ----------------
// grid 1024: b = blk>>4, chunk = (blk>>2)&3, csplit = blk&3
__global__ void ln_stats_kernel(const float* __restrict__ bcff,
                                float* __restrict__ psum, float* __restrict__ psumsq) {
  int blk = blockIdx.x;
  int cs = blk & 3, chunk = (blk >> 2) & 3, b = blk >> 4;
  int pos = chunk * 256 + (int)threadIdx.x;
  if (pos >= POS) return;
  const float* p = bcff + ((size_t)b * CE + cs * 192) * POS + pos;
  float s = 0.f, ss = 0.f;
#pragma unroll 8
  for (int c = 0; c < 192; ++c) {
    float v = p[(size_t)c * POS];
    s += v;
    ss += v * v;
  }
  int gp = b * POS + pos;
  psum[cs * M_TOT + gp] = s;
  psumsq[cs * M_TOT + gp] = ss;
}

// ---------------- kernel 3: LN + mask fill -> padded NHWC f16 ----------------
// grid NB*HP = 1920 blocks (b, ph). Border rows/cells -> zeros.
__global__ void ln_apply_kernel(const float* __restrict__ bcff, const int* __restrict__ act,
                                const float* __restrict__ mtok, const float* __restrict__ gamma,
                                const float* __restrict__ beta, const float* __restrict__ psum,
                                const float* __restrict__ psumsq, _Float16* __restrict__ xp) {
  int b = blockIdx.x / HP, ph = blockIdx.x % HP;
  _Float16* xrow = xp + ((size_t)(b * HP + ph)) * WP * CE;
  if (ph == 0 || ph == HP - 1) {
    // zero whole padded row: WP*CE halfs = 46080 B = 2880 uint4
    uint4* p = (uint4*)xrow;
    uint4 z = make_uint4(0, 0, 0, 0);
    for (int j = threadIdx.x; j < (WP * CE * 2) / 16; j += 256) p[j] = z;
    return;
  }
  int h = ph - 1;
  // zero the two border cells pw=0 and pw=WP-1 (768 halfs each = 96 uint4 each)
  {
    uint4 z = make_uint4(0, 0, 0, 0);
    uint4* p0 = (uint4*)xrow;                           // pw = 0
    uint4* p1 = (uint4*)(xrow + (size_t)(WP - 1) * CE); // pw = 29
    for (int j = threadIdx.x; j < (CE * 2) / 16; j += 256) { p0[j] = z; p1[j] = z; }
  }

  __shared__ float s_mean[WW], s_rstd[WW];
  __shared__ int s_act[WW];
  if (threadIdx.x < WW) {
    int gp = b * POS + h * WW + (int)threadIdx.x;
    float s = psum[gp] + psum[M_TOT + gp] + psum[2 * M_TOT + gp] + psum[3 * M_TOT + gp];
    float ss = psumsq[gp] + psumsq[M_TOT + gp] + psumsq[2 * M_TOT + gp] + psumsq[3 * M_TOT + gp];
    float mu = s * (1.f / 768.f);
    float var = ss * (1.f / 768.f) - mu * mu;
    s_mean[threadIdx.x] = mu;
    s_rstd[threadIdx.x] = rsqrtf(var + 1e-6f);
    s_act[threadIdx.x] = act[gp];
  }
  __syncthreads();

  __shared__ float tile[64 * 29]; // 64 channels x 28 w, pad 29 to kill bank conflicts
  for (int c0 = 0; c0 < CE; c0 += 64) {
    const float* src = bcff + ((size_t)(b * CE + c0) * HH + h) * WW;
    // load 64c x 28w, coalesced along w (112B runs per channel row)
#pragma unroll
    for (int i = threadIdx.x; i < 64 * WW; i += 256) {
      int cc = i / WW, w = i - cc * WW;
      tile[cc * 29 + w] = src[(size_t)cc * POS + w];
    }
    __syncthreads();
    // write NHWC coalesced: consecutive lanes -> consecutive c
#pragma unroll
    for (int i = threadIdx.x; i < 64 * WW; i += 256) {
      int w = i >> 6, cc = i & 63;
      int c = c0 + cc;
      float v;
      if (s_act[w])
        v = (tile[cc * 29 + w] - s_mean[w]) * s_rstd[w] * gamma[c] + beta[c];
      else
        v = mtok[c];
      xrow[(size_t)(w + 1) * CE + c] = (_Float16)v;
    }
    __syncthreads();
  }
}

// ---------------- kernel 4: implicit-GEMM conv via MFMA ----------------
// A[m][k]: m = (b,h,w) output position, k = tap*768+ci, read from padded NHWC x_pad
// Bmat[n][k]: wT[co][k]
// grid (392, 4), 256 threads (4 waves, 2x2), 128x128 tile, BK=32
__global__ void conv_gemm_kernel(const _Float16* __restrict__ xp, const _Float16* __restrict__ wT,
                                 const float* __restrict__ bias, float* __restrict__ out) {
  __shared__ _Float16 smem[8192]; // A: 128x32 (8KB) | B: 128x32 (8KB)
  char* sAb = (char*)smem;
  char* sBb = sAb + 8192;

  const int t = threadIdx.x;
  const int lane = t & 63, wv = t >> 6;
  const int m0 = blockIdx.x * 128;
  const int n0 = blockIdx.y * 128;

  // staging: slot s in [0,512): row r = s>>2 (32 halfs/row), ksub = (s&3)*8 halfs
  const int r0 = t >> 2;
  const int ks = (t & 3) * 8;
  const int m_a0 = m0 + r0;
  const int m_a1 = m0 + r0 + 64;
  int b0 = m_a0 / POS, p0 = m_a0 - b0 * POS;
  int b1 = m_a1 / POS, p1 = m_a1 - b1 * POS;
  int h0 = p0 / WW, w0 = p0 - h0 * WW;
  int h1 = p1 / WW, w1 = p1 - h1 * WW;
  const _Float16* gA0 = xp + ((size_t)((b0 * HP + h0) * WP + w0)) * CE + ks;
  const _Float16* gA1 = xp + ((size_t)((b1 * HP + h1) * WP + w1)) * CE + ks;
  const _Float16* gB0 = wT + (size_t)(n0 + r0) * K_TOT + ks;
  const _Float16* gB1 = wT + (size_t)(n0 + r0 + 64) * K_TOT + ks;

  // wave-uniform LDS bases for global_load_lds (dest = base + lane*16)
  char* ldsA0 = sAb + wv * 1024;
  char* ldsA1 = sAb + 4096 + wv * 1024;
  char* ldsB0 = sBb + wv * 1024;
  char* ldsB1 = sBb + 4096 + wv * 1024;

  const int wm = wv & 1, wn = wv >> 1;
  const int afrag_off = (wm * 64 + (lane & 15)) * 64 + (lane >> 4) * 16; // bytes
  const int bfrag_off = (wn * 64 + (lane & 15)) * 64 + (lane >> 4) * 16;

  f32x4 acc[4][4] = {};

  int aoff = 0, kin = 0, dw = 0;
  for (int kk = 0; kk < K_TOT / 32; ++kk) {
    // ---- stage A/B tiles (async direct-to-LDS, 16B/lane) ----
    __builtin_amdgcn_global_load_lds((__attribute__((address_space(1))) void*)(gA0 + aoff),
                                     (__attribute__((address_space(3))) void*)ldsA0, 16, 0, 0);
    __builtin_amdgcn_global_load_lds((__attribute__((address_space(1))) void*)(gA1 + aoff),
                                     (__attribute__((address_space(3))) void*)ldsA1, 16, 0, 0);
    __builtin_amdgcn_global_load_lds((__attribute__((address_space(1))) void*)(gB0 + kk * 32),
                                     (__attribute__((address_space(3))) void*)ldsB0, 16, 0, 0);
    __builtin_amdgcn_global_load_lds((__attribute__((address_space(1))) void*)(gB1 + kk * 32),
                                     (__attribute__((address_space(3))) void*)ldsB1, 16, 0, 0);
    __syncthreads(); // drains vmcnt -> staged data visible

    f16x8 af[4], bf[4];
#pragma unroll
    for (int i = 0; i < 4; ++i) af[i] = *(const f16x8*)(sAb + afrag_off + i * 1024);
#pragma unroll
    for (int i = 0; i < 4; ++i) bf[i] = *(const f16x8*)(sBb + bfrag_off + i * 1024);
#pragma unroll
    for (int mi = 0; mi < 4; ++mi)
#pragma unroll
      for (int ni = 0; ni < 4; ++ni)
        acc[mi][ni] = __builtin_amdgcn_mfma_f32_16x16x32_f16(af[mi], bf[ni], acc[mi][ni], 0, 0, 0);
    __syncthreads(); // all waves done reading before next stage overwrites

    // advance A offset through (tap, ci) space
    kin += 32; aoff += 32;
    if (kin == 768) { kin = 0; ++dw; if (dw == 3) { dw = 0; aoff += 27 * 768; } }
  }

  // ---- epilogue: D row = wm*64+mi*16+(lane>>4)*4+r, col = wn*64+ni*16+(lane&15) ----
  float bv[4];
#pragma unroll
  for (int ni = 0; ni < 4; ++ni) bv[ni] = bias[n0 + wn * 64 + ni * 16 + (lane & 15)];
#pragma unroll
  for (int mi = 0; mi < 4; ++mi) {
    int mbase = m0 + wm * 64 + mi * 16 + (lane >> 4) * 4;
#pragma unroll
    for (int r = 0; r < 4; ++r) {
      int m = mbase + r;
      int b = m / POS, pos = m - b * POS;
      float* orow = out + (size_t)b * CD * POS + pos;
#pragma unroll
      for (int ni = 0; ni < 4; ++ni) {
        int co = n0 + wn * 64 + ni * 16 + (lane & 15);
        orow[(size_t)co * POS] = acc[mi][ni][r] + bv[ni];
      }
    }
  }
}

extern "C" void kernel_launch(void* const* d_in, const int* in_sizes, int n_in,
                              void* d_out, int out_size, void* d_ws, size_t ws_size,
                              hipStream_t stream) {
  const float* bcff = (const float*)d_in[0];
  const int* cur_active = (const int*)d_in[1];
  const float* mask_token = (const float*)d_in[2];
  const float* ln_w = (const float*)d_in[3];
  const float* ln_b = (const float*)d_in[4];
  const float* conv_w = (const float*)d_in[5];
  const float* conv_b = (const float*)d_in[6];
  float* out = (float*)d_out;

  char* ws = (char*)d_ws;
  // x_pad: 64*30*30*768 f16 = 88,473,600 B
  _Float16* xp = (_Float16*)ws;
  // wT: 512*6912 f16 = 7,077,888 B
  _Float16* wT = (_Float16*)(ws + 88473600);
  // stats partials: 4 x 50176 floats each
  float* psum = (float*)(ws + 95551488);
  float* psumsq = (float*)(ws + 96354304);

  prep_w_kernel<<<dim3(CD), dim3(256), 0, stream>>>(conv_w, wT);
  ln_stats_kernel<<<dim3(1024), dim3(256), 0, stream>>>(bcff, psum, psumsq);
  ln_apply_kernel<<<dim3(NB * HP), dim3(256), 0, stream>>>(bcff, cur_active, mask_token,
                                                           ln_w, ln_b, psum, psumsq, xp);
  conv_gemm_kernel<<<dim3(M_TOT / 128, CD / 128), dim3(256), 0, stream>>>(xp, wT, conv_b, out);
}

// Round 2
// 777.541 us; speedup vs baseline: 1.1074x; 1.1074x over previous
//
#include <hip/hip_runtime.h>
#include <cstdint>
#include <cstddef>

#define CE 768
#define CD 512
#define NB 64
#define HH 28
#define WW 28
#define HP 30
#define WP 30
#define POS 784            // 28*28
#define M_TOT 50176        // 64*784
#define K_TOT 6912         // 9*768

typedef _Float16 f16x8 __attribute__((ext_vector_type(8)));
typedef _Float16 f16x4 __attribute__((ext_vector_type(4)));
typedef float f32x4 __attribute__((ext_vector_type(4)));

// ---------------- kernel 1: weight transpose + cast ----------------
// conv_w [CD][CE][3][3] fp32 -> wT [CD][9*CE] f16 with k = tap*CE + ci
__global__ void prep_w_kernel(const float* __restrict__ cw, _Float16* __restrict__ wT) {
  int co = blockIdx.x;
  const float* src = cw + (size_t)co * CE * 9;
  _Float16* dst = wT + (size_t)co * K_TOT;
  for (int j = threadIdx.x; j < K_TOT; j += blockDim.x) {
    int tap = j / CE;              // dh*3+dw
    int ci = j - tap * CE;
    dst[j] = (_Float16)src[ci * 9 + tap];
  }
}

// ---------------- kernel 2: fused LN + mask fill -> padded NHWC f16 ----------------
// grid NB*HP = 1920 blocks of 512 threads, block = (b, padded row ph).
// Border rows/cells -> zeros. Inner rows: load 768x28 fp32 tile to LDS once,
// reduce mean/rstd per w in-block, normalize (or mask-token), write f16x4 pairs.
__global__ void __launch_bounds__(512) ln_fused_kernel(
    const float* __restrict__ bcff, const int* __restrict__ act,
    const float* __restrict__ mtok, const float* __restrict__ gamma,
    const float* __restrict__ beta, _Float16* __restrict__ xp) {
  int b = blockIdx.x / HP, ph = blockIdx.x % HP;
  _Float16* xrow = xp + ((size_t)(b * HP + ph)) * WP * CE;
  const int tid = threadIdx.x;
  if (ph == 0 || ph == HP - 1) {
    uint4* p = (uint4*)xrow;
    uint4 z = make_uint4(0, 0, 0, 0);
    for (int j = tid; j < (WP * CE * 2) / 16; j += 512) p[j] = z;
    return;
  }
  int h = ph - 1;
  // zero border cells pw=0 and pw=29
  {
    uint4 z = make_uint4(0, 0, 0, 0);
    uint4* p0 = (uint4*)xrow;
    uint4* p1 = (uint4*)(xrow + (size_t)(WP - 1) * CE);
    for (int j = tid; j < (CE * 2) / 16; j += 512) { p0[j] = z; p1[j] = z; }
  }

  __shared__ float tile[CE * 29];   // 768 rows x 28 w, ld=29 (89,088 B)
  __shared__ float s_mean[WW], s_rstd[WW];
  __shared__ int s_act[WW];

  // ---- load whole (b,h) row: 768 channels x 28 w, coalesced along w ----
  const float* src = bcff + ((size_t)b * CE * HH + h) * WW;
#pragma unroll 6
  for (int i = tid; i < CE * WW; i += 512) {
    int cc = i / WW, w = i - cc * WW;
    tile[cc * 29 + w] = src[(size_t)cc * (HH * WW) + w];
  }
  if (tid < WW) s_act[tid] = act[b * POS + h * WW + tid];
  __syncthreads();

  // ---- stats: 16 threads per w (448 threads active) ----
  if (tid < WW * 16) {
    int w = tid >> 4, j = tid & 15;
    float s = 0.f, ss = 0.f;
#pragma unroll 8
    for (int c = j; c < CE; c += 16) {
      float v = tile[c * 29 + w];
      s += v; ss += v * v;
    }
#pragma unroll
    for (int d = 8; d; d >>= 1) {
      s += __shfl_down(s, d, 16);
      ss += __shfl_down(ss, d, 16);
    }
    if (j == 0) {
      float mu = s * (1.f / 768.f);
      float var = ss * (1.f / 768.f) - mu * mu;
      s_mean[w] = mu;
      s_rstd[w] = rsqrtf(var + 1e-6f);
    }
  }
  __syncthreads();

  // ---- normalize + mask fill, write f16x4 (4 consecutive channels) ----
  // item i: w = i/192, quad q = i%192 -> channels 4q..4q+3
  for (int i = tid; i < WW * 192; i += 512) {
    int w = i / 192, q = i - w * 192;
    int c = q * 4;
    f16x4 o;
    if (s_act[w]) {
      float mu = s_mean[w], rs = s_rstd[w];
#pragma unroll
      for (int j = 0; j < 4; ++j)
        o[j] = (_Float16)((tile[(c + j) * 29 + w] - mu) * rs * gamma[c + j] + beta[c + j]);
    } else {
#pragma unroll
      for (int j = 0; j < 4; ++j) o[j] = (_Float16)mtok[c + j];
    }
    *(f16x4*)(xrow + (size_t)(w + 1) * CE + c) = o;
  }
}

// ---------------- kernel 3: implicit-GEMM conv via MFMA ----------------
// A[m][k]: m = (b,h,w) output position, k = tap*768+ci, from padded NHWC x_pad
// Bmat[n][k] = wT[co][k]. grid (392,4), 256 thr (4 waves 2x2), 128x128 tile, BK=32.
// LDS XOR swizzle: chunk position p of row r holds ksub j = p ^ ((r>>1)&3)
// -> frag reads are 2-way-per-bank (free) instead of 8-way.
__global__ void conv_gemm_kernel(const _Float16* __restrict__ xp, const _Float16* __restrict__ wT,
                                 const float* __restrict__ bias, float* __restrict__ out) {
  __shared__ _Float16 smem[8192]; // A: 128x32 (8KB) | B: 128x32 (8KB)
  char* sAb = (char*)smem;
  char* sBb = sAb + 8192;

  const int t = threadIdx.x;
  const int lane = t & 63, wv = t >> 6;
  const int m0 = blockIdx.x * 128;
  const int n0 = blockIdx.y * 128;

  // staging: thread t -> row r0 = t>>2, LDS chunk position t&3.
  // source ksub chunk j = (t&3) ^ ((r0>>1)&3) = (t&3) ^ ((t>>3)&3)
  const int r0 = t >> 2;
  const int ks = (((t & 3) ^ ((t >> 3) & 3))) * 8; // halfs
  const int m_a0 = m0 + r0;
  const int m_a1 = m0 + r0 + 64;
  int b0 = m_a0 / POS, p0 = m_a0 - b0 * POS;
  int b1 = m_a1 / POS, p1 = m_a1 - b1 * POS;
  int h0 = p0 / WW, w0 = p0 - h0 * WW;
  int h1 = p1 / WW, w1 = p1 - h1 * WW;
  const _Float16* gA0 = xp + ((size_t)((b0 * HP + h0) * WP + w0)) * CE + ks;
  const _Float16* gA1 = xp + ((size_t)((b1 * HP + h1) * WP + w1)) * CE + ks;
  const _Float16* gB0 = wT + (size_t)(n0 + r0) * K_TOT + ks;
  const _Float16* gB1 = wT + (size_t)(n0 + r0 + 64) * K_TOT + ks;

  // wave-uniform LDS bases for global_load_lds (dest = base + lane*16)
  char* ldsA0 = sAb + wv * 1024;
  char* ldsA1 = sAb + 4096 + wv * 1024;
  char* ldsB0 = sBb + wv * 1024;
  char* ldsB1 = sBb + 4096 + wv * 1024;

  const int wm = wv & 1, wn = wv >> 1;
  // frag read: row = base + (lane&15) (+i*16), chunk = (lane>>4) ^ ((row>>1)&3);
  // base and i*16 are 0 mod 4 after >>1, so swizzle depends on (lane&15)>>1 only
  const int swz = ((lane >> 4) ^ (((lane & 15) >> 1) & 3)) * 16; // bytes
  const int afrag_off = (wm * 64 + (lane & 15)) * 64 + swz;
  const int bfrag_off = (wn * 64 + (lane & 15)) * 64 + swz;

  f32x4 acc[4][4] = {};

  int aoff = 0, kin = 0, dw = 0;
  for (int kk = 0; kk < K_TOT / 32; ++kk) {
    __builtin_amdgcn_global_load_lds((__attribute__((address_space(1))) void*)(gA0 + aoff),
                                     (__attribute__((address_space(3))) void*)ldsA0, 16, 0, 0);
    __builtin_amdgcn_global_load_lds((__attribute__((address_space(1))) void*)(gA1 + aoff),
                                     (__attribute__((address_space(3))) void*)ldsA1, 16, 0, 0);
    __builtin_amdgcn_global_load_lds((__attribute__((address_space(1))) void*)(gB0 + kk * 32),
                                     (__attribute__((address_space(3))) void*)ldsB0, 16, 0, 0);
    __builtin_amdgcn_global_load_lds((__attribute__((address_space(1))) void*)(gB1 + kk * 32),
                                     (__attribute__((address_space(3))) void*)ldsB1, 16, 0, 0);
    __syncthreads();

    f16x8 af[4], bf[4];
#pragma unroll
    for (int i = 0; i < 4; ++i) af[i] = *(const f16x8*)(sAb + afrag_off + i * 1024);
#pragma unroll
    for (int i = 0; i < 4; ++i) bf[i] = *(const f16x8*)(sBb + bfrag_off + i * 1024);
#pragma unroll
    for (int mi = 0; mi < 4; ++mi)
#pragma unroll
      for (int ni = 0; ni < 4; ++ni)
        acc[mi][ni] = __builtin_amdgcn_mfma_f32_16x16x32_f16(af[mi], bf[ni], acc[mi][ni], 0, 0, 0);
    __syncthreads();

    kin += 32; aoff += 32;
    if (kin == 768) { kin = 0; ++dw; if (dw == 3) { dw = 0; aoff += 27 * 768; } }
  }

  // ---- epilogue: acc[mi][ni][r] -> row mbase+r (4 consecutive pos) => f32x4 store
  float bv[4];
#pragma unroll
  for (int ni = 0; ni < 4; ++ni) bv[ni] = bias[n0 + wn * 64 + ni * 16 + (lane & 15)];
#pragma unroll
  for (int mi = 0; mi < 4; ++mi) {
    int mbase = m0 + wm * 64 + mi * 16 + (lane >> 4) * 4; // multiple of 4; 784%4==0
    int b = mbase / POS, pos = mbase - b * POS;           // all 4 rows same batch
    float* obase = out + (size_t)b * CD * POS + pos;
#pragma unroll
    for (int ni = 0; ni < 4; ++ni) {
      int co = n0 + wn * 64 + ni * 16 + (lane & 15);
      f32x4 v = acc[mi][ni];
      v += bv[ni];
      *(f32x4*)(obase + (size_t)co * POS) = v;
    }
  }
}

extern "C" void kernel_launch(void* const* d_in, const int* in_sizes, int n_in,
                              void* d_out, int out_size, void* d_ws, size_t ws_size,
                              hipStream_t stream) {
  const float* bcff = (const float*)d_in[0];
  const int* cur_active = (const int*)d_in[1];
  const float* mask_token = (const float*)d_in[2];
  const float* ln_w = (const float*)d_in[3];
  const float* ln_b = (const float*)d_in[4];
  const float* conv_w = (const float*)d_in[5];
  const float* conv_b = (const float*)d_in[6];
  float* out = (float*)d_out;

  char* ws = (char*)d_ws;
  _Float16* xp = (_Float16*)ws;                 // 64*30*30*768 f16 = 88,473,600 B
  _Float16* wT = (_Float16*)(ws + 88473600);    // 512*6912 f16 = 7,077,888 B

  prep_w_kernel<<<dim3(CD), dim3(256), 0, stream>>>(conv_w, wT);
  ln_fused_kernel<<<dim3(NB * HP), dim3(512), 0, stream>>>(bcff, cur_active, mask_token,
                                                           ln_w, ln_b, xp);
  conv_gemm_kernel<<<dim3(M_TOT / 128, CD / 128), dim3(256), 0, stream>>>(xp, wT, conv_b, out);
}

// Round 3
// 668.984 us; speedup vs baseline: 1.2871x; 1.1623x over previous
//
#include <hip/hip_runtime.h>
#include <cstdint>
#include <cstddef>

#define CE 768
#define CD 512
#define NB 64
#define HH 28
#define WW 28
#define HP 30
#define WP 30
#define POS 784            // 28*28
#define M_TOT 50176
#define K_TOT 6912         // 9*768
#define MP 57600           // 64*30*30 padded positions
#define XP_PIX 57728       // MP + slack for staging window overrun

typedef _Float16 f16x8 __attribute__((ext_vector_type(8)));
typedef _Float16 f16x4 __attribute__((ext_vector_type(4)));
typedef float f32x4 __attribute__((ext_vector_type(4)));

// ---------------- kernel 1: weight transpose + cast ----------------
// conv_w [CD][CE][3][3] fp32 -> wT [CD][9*CE] f16 with k = tap*CE + ci
__global__ void prep_w_kernel(const float* __restrict__ cw, _Float16* __restrict__ wT) {
  int co = blockIdx.x;
  const float* src = cw + (size_t)co * CE * 9;
  _Float16* dst = wT + (size_t)co * K_TOT;
  for (int j = threadIdx.x; j < K_TOT; j += blockDim.x) {
    int tap = j / CE;
    int ci = j - tap * CE;
    dst[j] = (_Float16)src[ci * 9 + tap];
  }
}

// ---------------- kernel 2: fused LN + mask fill -> padded NHWC f16 ----------------
// f16 LDS tile (44.5 KB) -> 3 blocks/CU (was fp32 89 KB -> 1 block/CU).
__global__ void __launch_bounds__(512) ln_fused_kernel(
    const float* __restrict__ bcff, const int* __restrict__ act,
    const float* __restrict__ mtok, const float* __restrict__ gamma,
    const float* __restrict__ beta, _Float16* __restrict__ xp) {
  int b = blockIdx.x / HP, ph = blockIdx.x % HP;
  _Float16* xrow = xp + ((size_t)(b * HP + ph)) * WP * CE;
  const int tid = threadIdx.x;
  if (ph == 0 || ph == HP - 1) {
    uint4* p = (uint4*)xrow;
    uint4 z = make_uint4(0, 0, 0, 0);
    for (int j = tid; j < (WP * CE * 2) / 16; j += 512) p[j] = z;
    return;
  }
  int h = ph - 1;
  {
    uint4 z = make_uint4(0, 0, 0, 0);
    uint4* p0 = (uint4*)xrow;
    uint4* p1 = (uint4*)(xrow + (size_t)(WP - 1) * CE);
    for (int j = tid; j < (CE * 2) / 16; j += 512) { p0[j] = z; p1[j] = z; }
  }

  __shared__ _Float16 tile[CE * 29];   // 44,544 B
  __shared__ float s_mean[WW], s_rstd[WW];
  __shared__ int s_act[WW];

  const float* src = bcff + ((size_t)b * CE * HH + h) * WW;
#pragma unroll 6
  for (int i = tid; i < CE * WW; i += 512) {
    int cc = i / WW, w = i - cc * WW;
    tile[cc * 29 + w] = (_Float16)src[(size_t)cc * (HH * WW) + w];
  }
  if (tid < WW) s_act[tid] = act[b * POS + h * WW + tid];
  __syncthreads();

  if (tid < WW * 16) {
    int w = tid >> 4, j = tid & 15;
    float s = 0.f, ss = 0.f;
#pragma unroll 8
    for (int c = j; c < CE; c += 16) {
      float v = (float)tile[c * 29 + w];
      s += v; ss += v * v;
    }
#pragma unroll
    for (int d = 8; d; d >>= 1) {
      s += __shfl_down(s, d, 16);
      ss += __shfl_down(ss, d, 16);
    }
    if (j == 0) {
      float mu = s * (1.f / 768.f);
      float var = ss * (1.f / 768.f) - mu * mu;
      s_mean[w] = mu;
      s_rstd[w] = rsqrtf(var + 1e-6f);
    }
  }
  __syncthreads();

  for (int i = tid; i < WW * 192; i += 512) {
    int w = i / 192, q = i - w * 192;
    int c = q * 4;
    f16x4 o;
    if (s_act[w]) {
      float mu = s_mean[w], rs = s_rstd[w];
#pragma unroll
      for (int j = 0; j < 4; ++j)
        o[j] = (_Float16)(((float)tile[(c + j) * 29 + w] - mu) * rs * gamma[c + j] + beta[c + j]);
    } else {
#pragma unroll
      for (int j = 0; j < 4; ++j) o[j] = (_Float16)mtok[c + j];
    }
    *(f16x4*)(xrow + (size_t)(w + 1) * CE + c) = o;
  }
}

// ---------------- kernel 3: strip implicit-GEMM conv ----------------
// M' = padded pixel space (57600). Tile: 128 padded rows x 64 cols.
// Outer loop: 24 ci-chunks of 32. Per chunk: stage A window (192 pixels x 64B,
// serves ALL 9 taps via tap-shifted LDS reads) + B for all 9 taps (36 KB).
// 36 MFMA per barrier-pair per wave. nb = blockIdx&7 pins each XCD to one
// 884 KB B panel -> L2-resident B.
#define GLDS(src, dst) __builtin_amdgcn_global_load_lds( \
    (const __attribute__((address_space(1))) void*)(src), \
    (__attribute__((address_space(3))) void*)(dst), 16, 0, 0)

__global__ void __launch_bounds__(512) conv_strip_kernel(
    const _Float16* __restrict__ xp, const _Float16* __restrict__ wT,
    const float* __restrict__ bias, float* __restrict__ out) {
  __shared__ _Float16 smem[24576];    // A: 192*64B = 12 KB | B: 9*4 KB = 36 KB
  char* sAb = (char*)smem;
  char* sBb = sAb + 12288;

  const int t = threadIdx.x;
  const int lane = t & 63, wv = t >> 6;
  const int nb = blockIdx.x & 7;            // XCD-pinned n panel
  const int mb = blockIdx.x >> 3;
  const int p0 = mb * 128;
  const int n0 = nb * 64;

  // ---- staging maps (slot s -> LDS byte s*16; source chunk XOR-swizzled) ----
  const int jj = (t & 3) ^ ((t >> 3) & 3);  // source k-chunk 0..3
  const int pixA = t >> 2;                  // A pixels 0..127 (round0), +128 (round1)
  const _Float16* pA0 = xp + (size_t)(p0 + pixA) * CE + jj * 8;
  const _Float16* pA1 = pA0 + (size_t)128 * CE;
  const int rowB = (t >> 2) & 63;
  const int hiB = t >> 8;                   // 0/1
  const _Float16* pB = wT + (size_t)(n0 + rowB) * K_TOT + jj * 8;
  char* dA0 = sAb + wv * 1024;
  char* dA1 = sAb + 8192 + wv * 1024;
  char* dB0 = sBb + wv * 1024;

  // ---- fragment maps ----
  const int wm = wv >> 1, wn = wv & 1;      // 4 x 2 wave grid, wave = 32m x 32n
  const int rowbase0 = wm * 32 + (lane & 15);
  const int lq = lane >> 4;
  const int bfrag_off = (wn * 32 + (lane & 15)) * 64 +
                        ((lq ^ (((lane & 15) >> 1) & 3)) * 16);

  f32x4 acc[2][2] = {};
  const int tap_off[9] = {0, 1, 2, 30, 31, 32, 60, 61, 62};

  for (int c24 = 0; c24 < 24; ++c24) {
    const int koff = c24 * 32;  // halfs
    GLDS(pA0 + koff, dA0);
    if (wv < 4) GLDS(pA1 + koff, dA1);
#pragma unroll
    for (int k = 0; k < 4; ++k)
      GLDS(pB + (2 * k + hiB) * CE + koff, dB0 + 8192 * k);
    if (wv < 4) GLDS(pB + 8 * CE + koff, dB0 + 32768);
    __syncthreads();

#pragma unroll
    for (int tap = 0; tap < 9; ++tap) {
      const int rA = rowbase0 + tap_off[tap];
      const char* aptr = sAb + rA * 64 + ((lq ^ ((rA >> 1) & 3)) * 16);
      f16x8 a0 = *(const f16x8*)(aptr);
      f16x8 a1 = *(const f16x8*)(aptr + 1024);
      const char* bptr = sBb + tap * 4096 + bfrag_off;
      f16x8 b0 = *(const f16x8*)(bptr);
      f16x8 b1 = *(const f16x8*)(bptr + 1024);
      acc[0][0] = __builtin_amdgcn_mfma_f32_16x16x32_f16(a0, b0, acc[0][0], 0, 0, 0);
      acc[0][1] = __builtin_amdgcn_mfma_f32_16x16x32_f16(a0, b1, acc[0][1], 0, 0, 0);
      acc[1][0] = __builtin_amdgcn_mfma_f32_16x16x32_f16(a1, b0, acc[1][0], 0, 0, 0);
      acc[1][1] = __builtin_amdgcn_mfma_f32_16x16x32_f16(a1, b1, acc[1][1], 0, 0, 0);
    }
    __syncthreads();
  }

  // ---- epilogue: mask pad rows, f32x4 fast path ----
  float bv[2];
#pragma unroll
  for (int ni = 0; ni < 2; ++ni) bv[ni] = bias[n0 + wn * 32 + ni * 16 + (lane & 15)];
#pragma unroll
  for (int mi = 0; mi < 2; ++mi) {
    int g = p0 + wm * 32 + mi * 16 + (lane >> 4) * 4;  // 4-aligned padded index
    int b = g / 900;
    int q = g - b * 900;
    int ph = q / 30, pw = q - ph * 30;                 // pw even
#pragma unroll
    for (int ni = 0; ni < 2; ++ni) {
      int co = n0 + wn * 32 + ni * 16 + (lane & 15);
      f32x4 v = acc[mi][ni];
      v += bv[ni];
      float* obase = out + ((size_t)b * CD + co) * POS;
      if (b < NB && ph < 28) {
        if (pw <= 24) {
          *(f32x4*)(obase + ph * 28 + pw) = v;
        } else if (pw == 26) {
          obase[ph * 28 + 26] = v[0];
          obase[ph * 28 + 27] = v[1];
        }
      }
      if (pw == 28) {      // elements r=2,3 roll into next image row (maybe next b)
        int b2 = b, ph2 = ph + 1;
        if (ph2 == 30) { b2++; ph2 = 0; }
        if (b2 < NB && ph2 < 28) {
          float* o2 = out + ((size_t)b2 * CD + co) * POS + ph2 * 28;
          o2[0] = v[2];
          o2[1] = v[3];
        }
      }
    }
  }
}

extern "C" void kernel_launch(void* const* d_in, const int* in_sizes, int n_in,
                              void* d_out, int out_size, void* d_ws, size_t ws_size,
                              hipStream_t stream) {
  const float* bcff = (const float*)d_in[0];
  const int* cur_active = (const int*)d_in[1];
  const float* mask_token = (const float*)d_in[2];
  const float* ln_w = (const float*)d_in[3];
  const float* ln_b = (const float*)d_in[4];
  const float* conv_w = (const float*)d_in[5];
  const float* conv_b = (const float*)d_in[6];
  float* out = (float*)d_out;

  char* ws = (char*)d_ws;
  _Float16* xp = (_Float16*)ws;                       // XP_PIX*768*2 = 88,670,208 B
  _Float16* wT = (_Float16*)(ws + (size_t)XP_PIX * CE * 2);  // 7,077,888 B

  prep_w_kernel<<<dim3(CD), dim3(256), 0, stream>>>(conv_w, wT);
  ln_fused_kernel<<<dim3(NB * HP), dim3(512), 0, stream>>>(bcff, cur_active, mask_token,
                                                           ln_w, ln_b, xp);
  // 450 m-blocks x 8 n-blocks; nb = blockIdx & 7 -> one B panel per XCD
  conv_strip_kernel<<<dim3(450 * 8), dim3(512), 0, stream>>>(xp, wT, conv_b, out);
}